// Round 19
// baseline (295.727 us; speedup 1.0000x reference)
//
#include <hip/hip_runtime.h>
#include <hip/hip_bf16.h>
#include <stdint.h>

typedef __bf16 bf16x8 __attribute__((ext_vector_type(8)));
typedef __bf16 bf16x4 __attribute__((ext_vector_type(4)));
typedef short  s16x4  __attribute__((ext_vector_type(4)));
typedef float  f32x4  __attribute__((ext_vector_type(4)));
typedef unsigned short u16;

__device__ __forceinline__ u16 f2bf(float f) {
    return __builtin_bit_cast(u16, (__bf16)f);
}

__device__ __forceinline__ f32x4 vexp4(f32x4 a) {
    f32x4 r;
    r[0] = __expf(a[0]); r[1] = __expf(a[1]);
    r[2] = __expf(a[2]); r[3] = __expf(a[3]);
    return r;
}

// 16x16x16 bf16 MFMA (A/B = 4 bf16 = 2 VGPRs each)
__device__ __forceinline__ f32x4 mfma16(bf16x4 a, bf16x4 b, f32x4 c) {
#if __has_builtin(__builtin_amdgcn_mfma_f32_16x16x16bf16_1k)
    return __builtin_amdgcn_mfma_f32_16x16x16bf16_1k(
        __builtin_bit_cast(s16x4, a), __builtin_bit_cast(s16x4, b), c, 0, 0, 0);
#else
    f32x4 d;
    asm volatile("v_mfma_f32_16x16x16_bf16 %0, %1, %2, %3"
                 : "=v"(d) : "v"(a), "v"(b), "v"(c));
    return d;
#endif
}

// async global->LDS, 16B/lane; lds dst is wave-uniform base (+lane*16 implicit)
__device__ __forceinline__ void stage16(const void* g, void* lds_wave_base) {
#if __has_builtin(__builtin_amdgcn_global_load_lds)
    __builtin_amdgcn_global_load_lds(
        (const __attribute__((address_space(1))) void*)g,
        (__attribute__((address_space(3))) void*)lds_wave_base, 16, 0, 0);
#else
    int lane = threadIdx.x & 63;
    *(uint4*)((char*)lds_wave_base + lane * 16) = *(const uint4*)g;
#endif
}

// LDS row swizzle (128B rows): XOR bits 4-6 of the in-row byte offset
__device__ __forceinline__ int swz(int r) {
    return (((r) & 7) ^ (((r) >> 3) & 7)) << 4;
}

// ---------------------------------------------------------------------------
// pack1: qkv weights (wq scaled 0.125) + wo -> bf16; FFN weights too when
// do_ffn (big path; removes the separate pack2 launch).
// ---------------------------------------------------------------------------
__global__ void pack1_kernel(const float* __restrict__ wq, const float* __restrict__ wk,
                             const float* __restrict__ wv, const float* __restrict__ bq,
                             const float* __restrict__ bk, const float* __restrict__ bv,
                             const float* __restrict__ wo, const float* __restrict__ w1,
                             const float* __restrict__ w2,
                             u16* __restrict__ wqkv, float* __restrict__ bqkv,
                             u16* __restrict__ wo_b, u16* __restrict__ w1_b,
                             u16* __restrict__ w2_b, int do_ffn) {
    const float QS = 0.125f;
    size_t i0 = (size_t)blockIdx.x * 256 + threadIdx.x;
    size_t stride = (size_t)gridDim.x * 256;
    const size_t DD = 1024u * 1024u;
    for (size_t i = i0; i < 3 * DD; i += stride) {
        float v;
        if (i < DD)          v = wq[i] * QS;
        else if (i < 2 * DD) v = wk[i - DD];
        else                 v = wv[i - 2 * DD];
        wqkv[i] = f2bf(v);
    }
    for (size_t i = i0; i < DD; i += stride) wo_b[i] = f2bf(wo[i]);
    if (do_ffn) {
        for (size_t i = i0; i < 4 * DD; i += stride) w1_b[i] = f2bf(w1[i]);
        for (size_t i = i0; i < 4 * DD; i += stride) w2_b[i] = f2bf(w2[i]);
    }
    for (size_t i = i0; i < 3072; i += stride)
        bqkv[i] = (i < 1024) ? bq[i] * QS : ((i < 2048) ? bk[i - 1024] : bv[i - 2048]);
}

// pack2: FFN weights -> bf16 (small path only: runs after O-proj, region reuse)
__global__ void pack2_kernel(const float* __restrict__ w1, const float* __restrict__ w2,
                             u16* __restrict__ w1_b, u16* __restrict__ w2_b) {
    size_t i0 = (size_t)blockIdx.x * 256 + threadIdx.x;
    size_t stride = (size_t)gridDim.x * 256;
    const size_t DD = 1024u * 1024u;
    for (size_t i = i0; i < 4 * DD; i += stride) w1_b[i] = f2bf(w1[i]);
    for (size_t i = i0; i < 4 * DD; i += stride) w2_b[i] = f2bf(w2[i]);
}

// ---------------------------------------------------------------------------
// LayerNorm: per-row (1024), scalar alpha/bias, ddof=1, eps added to std
// ---------------------------------------------------------------------------
__global__ __launch_bounds__(256)
void ln_kernel(const float* __restrict__ x, u16* __restrict__ out,
               const float* __restrict__ alpha, const float* __restrict__ beta) {
    const int row = blockIdx.x;
    const int t = threadIdx.x, lane = t & 63, w = t >> 6;
    float4 v = ((const float4*)(x + (size_t)row * 1024))[t];
    float s  = v.x + v.y + v.z + v.w;
    float ss = v.x * v.x + v.y * v.y + v.z * v.z + v.w * v.w;
#pragma unroll
    for (int d = 1; d < 64; d <<= 1) { s += __shfl_xor(s, d); ss += __shfl_xor(ss, d); }
    __shared__ float red[8];
    if (lane == 0) { red[w] = s; red[4 + w] = ss; }
    __syncthreads();
    s  = red[0] + red[1] + red[2] + red[3];
    ss = red[4] + red[5] + red[6] + red[7];
    const float mu  = s * (1.f / 1024.f);
    const float var = fmaxf((ss - 1024.f * mu * mu) * (1.f / 1023.f), 0.f);
    const float inv = alpha[0] / (sqrtf(var) + 1e-6f);
    const float bb  = beta[0];
    ushort4 o;
    o.x = f2bf((v.x - mu) * inv + bb);
    o.y = f2bf((v.y - mu) * inv + bb);
    o.z = f2bf((v.z - mu) * inv + bb);
    o.w = f2bf((v.w - mu) * inv + bb);
    ((ushort4*)(out + (size_t)row * 1024))[t] = o;
}

// ---------------------------------------------------------------------------
// GEMM 128x128 2-phase, 4 waves (proven): C = A * B^T + bias. BK=32.
// EPI: 0 = bf16 out; 1 = bf16 relu; 2 = f32 out + resid
// ---------------------------------------------------------------------------
template <int EPI>
__global__ __launch_bounds__(256)
void gemm_bt(const u16* __restrict__ A, const u16* __restrict__ B,
             const float* __restrict__ bias, const float* __restrict__ resid,
             void* __restrict__ Cout, int M, int N, int K, int ldc) {
    __shared__ __align__(16) char As[16384];   // 2 x 8192
    __shared__ __align__(16) char Bs[16384];
    const int t = threadIdx.x;
    const int lane = t & 63, wave = t >> 6;
    const int g = lane >> 4, c = lane & 15;
    const int wm = wave >> 1, wn = wave & 1;
    const int bm = blockIdx.x, bn = blockIdx.y;

    const f32x4 z4 = {0.f, 0.f, 0.f, 0.f};
    f32x4 acc[4][4];
#pragma unroll
    for (int m = 0; m < 4; ++m)
#pragma unroll
        for (int n = 0; n < 4; ++n) acc[m][n] = z4;

    const int srow = t >> 2;
    const int ak = (((t & 3) ^ ((t >> 2) & 3)) << 3);
    const u16* ga = A + (size_t)(bm * 128 + srow) * K + ak;
    const u16* gb = B + (size_t)(bn * 128 + srow) * K + ak;
    const size_t rstep = (size_t)64 * K;

    auto STAGE = [&](int k0, int buf) {
        char* la = As + buf * 8192 + wave * 1024;
        char* lb = Bs + buf * 8192 + wave * 1024;
        stage16(ga + k0,         la);
        stage16(ga + k0 + rstep, la + 4096);
        stage16(gb + k0,         lb);
        stage16(gb + k0 + rstep, lb + 4096);
    };

    STAGE(0, 0);
    asm volatile("s_waitcnt vmcnt(0)" ::: "memory");
    __syncthreads();

    int cur = 0;
    for (int k0 = 0; k0 < K; k0 += 32) {
        if (k0 + 32 < K) STAGE(k0 + 32, cur ^ 1);
        const char* Ac = As + cur * 8192;
        const char* Bc = Bs + cur * 8192;
        bf16x8 a[4], b[4];
#pragma unroll
        for (int m = 0; m < 4; ++m) {
            int r = wm * 64 + m * 16 + c;
            a[m] = *(const bf16x8*)(Ac + r * 64 + ((g * 16) ^ ((c & 3) << 4)));
        }
#pragma unroll
        for (int n = 0; n < 4; ++n) {
            int r = wn * 64 + n * 16 + c;
            b[n] = *(const bf16x8*)(Bc + r * 64 + ((g * 16) ^ ((c & 3) << 4)));
        }
        __builtin_amdgcn_s_setprio(1);
#pragma unroll
        for (int m = 0; m < 4; ++m)
#pragma unroll
            for (int n = 0; n < 4; ++n)
                acc[m][n] = __builtin_amdgcn_mfma_f32_16x16x32_bf16(a[m], b[n], acc[m][n], 0, 0, 0);
        __builtin_amdgcn_s_setprio(0);
        asm volatile("s_waitcnt vmcnt(0)" ::: "memory");
        __syncthreads();
        cur ^= 1;
    }

    const int row0 = bm * 128 + wm * 64;
    const int col0 = bn * 128 + wn * 64;
#pragma unroll
    for (int m = 0; m < 4; ++m) {
#pragma unroll
        for (int n = 0; n < 4; ++n) {
            const int cc = col0 + n * 16 + c;
            const float bv = bias[cc];
#pragma unroll
            for (int j = 0; j < 4; ++j) {
                const int rr = row0 + m * 16 + g * 4 + j;
                float v = acc[m][n][j] + bv;
                if (EPI == 1) v = v > 0.f ? v : 0.f;
                if (EPI == 2) {
                    ((float*)Cout)[(size_t)rr * ldc + cc] = resid[(size_t)rr * ldc + cc] + v;
                } else {
                    ((u16*)Cout)[(size_t)rr * ldc + cc] = f2bf(v);
                }
            }
        }
    }
}

// ---------------------------------------------------------------------------
// GEMM 256x256 8-wave 4-phase: C = A*B^T + bias, BK=64. 512 thr (2M x 4N).
// LDS 128KB dynamic. Raw s_barrier per phase; vmcnt(0)+barrier per K-tile.
// EPI: 0 = bf16 out; 1 = bf16 relu.  Grid: 1-D gm*gn, XCD-swizzled (nb%8==0).
// ---------------------------------------------------------------------------
template <int EPI>
__global__ __launch_bounds__(512)
void gemm256(const u16* __restrict__ A, const u16* __restrict__ B,
             const float* __restrict__ bias, u16* __restrict__ Cout,
             int K, int ldc, int gm) {
    extern __shared__ __align__(16) char lds[];
    char* As0 = lds;              // 2 x 32768
    char* Bs0 = lds + 65536;      // 2 x 32768
    const int t = threadIdx.x, lane = t & 63, wave = t >> 6;
    const int g = lane >> 4, c = lane & 15;
    const int wm = wave >> 2, wn = wave & 3;
    const int f = blockIdx.x, nb = gridDim.x;
    const int sw = (f & 7) * (nb >> 3) + (f >> 3);
    const int bm = sw % gm, bn = sw / gm;

    const f32x4 z4 = {0.f, 0.f, 0.f, 0.f};
    f32x4 acc[8][4];
#pragma unroll
    for (int mi = 0; mi < 8; ++mi)
#pragma unroll
        for (int ni = 0; ni < 4; ++ni) acc[mi][ni] = z4;

    auto STAGE = [&](const u16* G, int base_row, int k0, char* dst, int half) {
#pragma unroll
        for (int l = 0; l < 2; ++l) {
            int idx = half * 1024 + l * 512 + t;
            int row = idx >> 3, p = idx & 7;
            stage16(G + (size_t)(base_row + row) * K + k0 + ((p ^ (row & 7)) << 3),
                    dst + (half * 1024 + l * 512 + wave * 64) * 16);
        }
    };
    auto ldA = [&](int buf, int mi, int ks) -> bf16x8 {
        int r = wm * 128 + mi * 16 + c;
        return *(const bf16x8*)(As0 + buf * 32768 + r * 128 + ((((ks << 2) + g) ^ (r & 7)) << 4));
    };
    auto ldB = [&](int buf, int ni, int ks) -> bf16x8 {
        int r = wn * 64 + ni * 16 + c;
        return *(const bf16x8*)(Bs0 + buf * 32768 + r * 128 + ((((ks << 2) + g) ^ (r & 7)) << 4));
    };

    const int NT = K >> 6;
    STAGE(A, bm * 256, 0, As0, 0); STAGE(A, bm * 256, 0, As0, 1);
    STAGE(B, bn * 256, 0, Bs0, 0); STAGE(B, bn * 256, 0, Bs0, 1);
    asm volatile("s_waitcnt vmcnt(0)" ::: "memory");
    __builtin_amdgcn_s_barrier();

    int cur = 0;
    for (int kt = 0; kt < NT; ++kt) {
        const int k0n = (kt + 1) << 6;
        const bool more = kt + 1 < NT;
        bf16x8 bfr[4][2];
#pragma unroll
        for (int ni = 0; ni < 4; ++ni) {
            bfr[ni][0] = ldB(cur, ni, 0);
            bfr[ni][1] = ldB(cur, ni, 1);
        }
#pragma unroll
        for (int ph = 0; ph < 4; ++ph) {
            bf16x8 a0k0 = ldA(cur, 2 * ph, 0),     a0k1 = ldA(cur, 2 * ph, 1);
            bf16x8 a1k0 = ldA(cur, 2 * ph + 1, 0), a1k1 = ldA(cur, 2 * ph + 1, 1);
            if (more && ph == 0) {
                STAGE(A, bm * 256, k0n, As0 + (cur ^ 1) * 32768, 0);
                STAGE(A, bm * 256, k0n, As0 + (cur ^ 1) * 32768, 1);
            }
            if (more && ph == 1) {
                STAGE(B, bn * 256, k0n, Bs0 + (cur ^ 1) * 32768, 0);
                STAGE(B, bn * 256, k0n, Bs0 + (cur ^ 1) * 32768, 1);
            }
            __builtin_amdgcn_s_barrier();
            __builtin_amdgcn_s_setprio(1);
#pragma unroll
            for (int ni = 0; ni < 4; ++ni) {
                acc[2 * ph][ni]     = __builtin_amdgcn_mfma_f32_16x16x32_bf16(a0k0, bfr[ni][0], acc[2 * ph][ni], 0, 0, 0);
                acc[2 * ph][ni]     = __builtin_amdgcn_mfma_f32_16x16x32_bf16(a0k1, bfr[ni][1], acc[2 * ph][ni], 0, 0, 0);
                acc[2 * ph + 1][ni] = __builtin_amdgcn_mfma_f32_16x16x32_bf16(a1k0, bfr[ni][0], acc[2 * ph + 1][ni], 0, 0, 0);
                acc[2 * ph + 1][ni] = __builtin_amdgcn_mfma_f32_16x16x32_bf16(a1k1, bfr[ni][1], acc[2 * ph + 1][ni], 0, 0, 0);
            }
            __builtin_amdgcn_s_setprio(0);
            __builtin_amdgcn_s_barrier();
        }
        asm volatile("s_waitcnt vmcnt(0)" ::: "memory");
        __builtin_amdgcn_s_barrier();
        cur ^= 1;
    }

    const int row0 = bm * 256 + wm * 128;
    const int col0 = bn * 256 + wn * 64;
#pragma unroll
    for (int mi = 0; mi < 8; ++mi) {
#pragma unroll
        for (int ni = 0; ni < 4; ++ni) {
            const int cc = col0 + ni * 16 + c;
            const float bv = bias[cc];
#pragma unroll
            for (int j = 0; j < 4; ++j) {
                const int rr = row0 + mi * 16 + g * 4 + j;
                float v = acc[mi][ni][j] + bv;
                if (EPI == 1) v = v > 0.f ? v : 0.f;
                Cout[(size_t)rr * ldc + cc] = f2bf(v);
            }
        }
    }
}

// ---------------------------------------------------------------------------
// Flash attention: QBLK=64 (4 waves x 16 q), KVBLK=64, grid 1024, XCD-swz.
// LDS 24KB: K double-buffered (2x8KB), V single-buffered (8KB, 128B rows).
// -> 4 blocks/CU resident (single balanced round, 16 waves/CU).
// FIXED-MAX softmax (m==0); l per-lane partial, reduced once in epilogue.
// qkv: [4096,3072] bf16 (q|k|v), q pre-scaled by 0.125. out: [4096,1024] bf16
// ---------------------------------------------------------------------------
__global__ __launch_bounds__(256)
void attn_kernel(const u16* __restrict__ qkv, const int* __restrict__ mask,
                 u16* __restrict__ attn_out) {
    __shared__ __align__(16) char Ksm[16384];   // 2 x [64 k][128 B], src-preswizzled
    __shared__ __align__(16) char Vsm[8192];    // [64 d][64 k x 2B = 128 B], swz
    const int t = threadIdx.x, lane = t & 63, w = t >> 6;
    const int g = lane >> 4, c = lane & 15;
    const int flat = blockIdx.x;
    const int xcd = flat & 7, u = flat >> 3;
    const int qt = u & 31;
    const int p = xcd * 4 + (u >> 5);
    const int h = p & 15, b = p >> 4;
    const int S = 2048, LD = 3072;
    const int NT = S / 64;                      // 32 k-tiles of 64

    bf16x8 qf[2];
#pragma unroll
    for (int half = 0; half < 2; ++half)
        qf[half] = *(const bf16x8*)&qkv[(size_t)(b * S + qt * 64 + w * 16 + c) * LD
                                        + h * 64 + half * 32 + g * 8];

    const f32x4 z4 = {0.f, 0.f, 0.f, 0.f};
    f32x4 accO[4];
#pragma unroll
    for (int dt = 0; dt < 4; ++dt) accO[dt] = z4;
    f32x4 lrun4 = z4;                       // per-lane partial sum of P

    unsigned vr[8];
    const int vd0 = (t & 31) * 2;           // d pair (0..62)
    const int vkg = t >> 5;                 // k group (0..7), 8 k each

    auto STAGEK = [&](int kt, char* Kd) {
#pragma unroll
        for (int it = 0; it < 2; ++it) {
            int idx = it * 256 + t;
            int k = idx >> 3, pp = idx & 7;
            int ps = pp ^ ((k & 7) ^ ((k >> 3) & 7));
            stage16(&qkv[(size_t)(b * S + kt * 64 + k) * LD + 1024 + h * 64 + ps * 8],
                    Kd + (it * 256 + w * 64) * 16);
        }
    };
    auto VLOAD = [&](int kt) {
        const u16* src = &qkv[(size_t)(b * S + kt * 64 + vkg * 8) * LD + 2048 + h * 64 + vd0];
#pragma unroll
        for (int i = 0; i < 8; ++i)
            vr[i] = *(const unsigned*)(src + (size_t)i * LD);
    };
    auto VWRITE = [&]() {
        uint4 lo, hi;
        lo.x = (vr[0] & 0xffffu) | (vr[1] << 16);
        lo.y = (vr[2] & 0xffffu) | (vr[3] << 16);
        lo.z = (vr[4] & 0xffffu) | (vr[5] << 16);
        lo.w = (vr[6] & 0xffffu) | (vr[7] << 16);
        hi.x = (vr[0] >> 16) | (vr[1] & 0xffff0000u);
        hi.y = (vr[2] >> 16) | (vr[3] & 0xffff0000u);
        hi.z = (vr[4] >> 16) | (vr[5] & 0xffff0000u);
        hi.w = (vr[6] >> 16) | (vr[7] & 0xffff0000u);
        *(uint4*)(Vsm + vd0 * 128 + ((vkg * 16) ^ swz(vd0)))           = lo;
        *(uint4*)(Vsm + (vd0 + 1) * 128 + ((vkg * 16) ^ swz(vd0 + 1))) = hi;
    };

    STAGEK(0, Ksm);
    VLOAD(0);
    asm volatile("s_waitcnt vmcnt(0)" ::: "memory");
    VWRITE();
    __syncthreads();

    int cur = 0;
    for (int kt = 0; kt < NT; ++kt) {
        char* Kc = Ksm + cur * 8192;
        if (kt + 1 < NT) {
            STAGEK(kt + 1, Ksm + (cur ^ 1) * 8192);
            VLOAD(kt + 1);
        }

        f32x4 s[4];
        __builtin_amdgcn_s_setprio(1);
#pragma unroll
        for (int n = 0; n < 4; ++n) {
            int kr = n * 16 + c;
            bf16x8 k0 = *(const bf16x8*)(Kc + kr * 128 + ((g * 16) ^ swz(kr)));
            bf16x8 k1 = *(const bf16x8*)(Kc + kr * 128 + ((64 + g * 16) ^ swz(kr)));
            s[n] = __builtin_amdgcn_mfma_f32_16x16x32_bf16(k0, qf[0], z4, 0, 0, 0);
            s[n] = __builtin_amdgcn_mfma_f32_16x16x32_bf16(k1, qf[1], s[n], 0, 0, 0);
        }
        __builtin_amdgcn_s_setprio(0);
#pragma unroll
        for (int n = 0; n < 4; ++n) {
            int4 mv = *(const int4*)&mask[b * S + kt * 64 + n * 16 + g * 4];
            if (mv.x == 0) s[n][0] = -1e9f;
            if (mv.y == 0) s[n][1] = -1e9f;
            if (mv.z == 0) s[n][2] = -1e9f;
            if (mv.w == 0) s[n][3] = -1e9f;
        }
        // fixed-max softmax: P = exp(s); accumulate per-lane partial l
#pragma unroll
        for (int n = 0; n < 4; ++n) { s[n] = vexp4(s[n]); lrun4 += s[n]; }
        __builtin_amdgcn_s_setprio(1);
#pragma unroll
        for (int n = 0; n < 4; ++n) {
            bf16x4 p0;
#pragma unroll
            for (int j = 0; j < 4; ++j) p0[j] = (__bf16)s[n][j];
#pragma unroll
            for (int dt = 0; dt < 4; ++dt) {
                int d = dt * 16 + c;
                bf16x4 vf = *(const bf16x4*)(Vsm + d * 128 + ((n * 32 + g * 8) ^ swz(d)));
                accO[dt] = mfma16(vf, p0, accO[dt]);
            }
        }
        __builtin_amdgcn_s_setprio(0);

        __syncthreads();
        asm volatile("s_waitcnt vmcnt(0)" ::: "memory");
        if (kt + 1 < NT) VWRITE();
        __syncthreads();
        cur ^= 1;
    }

    // epilogue: reduce l across the 4 covering lanes (once), normalize, store
    char* Osm = Ksm;   // [64 q][128 B] = 8KB
    {
        float l = lrun4[0] + lrun4[1] + lrun4[2] + lrun4[3];
        l += __shfl_xor(l, 16);
        l += __shfl_xor(l, 32);
        float inv = 1.f / l;
        int ql = w * 16 + c;
#pragma unroll
        for (int dt = 0; dt < 4; ++dt)
#pragma unroll
            for (int j = 0; j < 4; ++j) {
                int d = dt * 16 + g * 4 + j;
                *(u16*)(Osm + ql * 128 + ((d * 2) ^ swz(ql))) = f2bf(accO[dt][j] * inv);
            }
    }
    __syncthreads();
#pragma unroll
    for (int it = 0; it < 2; ++it) {
        int idx = it * 256 + t;
        int q = idx >> 3, pp = idx & 7;
        uint4 val = *(const uint4*)(Osm + q * 128 + ((pp * 16) ^ swz(q)));
        *(uint4*)&attn_out[(size_t)(b * S + qt * 64 + q) * 1024 + h * 64 + pp * 8] = val;
    }
}

// ---------------------------------------------------------------------------
extern "C" void kernel_launch(void* const* d_in, const int* in_sizes, int n_in,
                              void* d_out, int out_size, void* d_ws, size_t ws_size,
                              hipStream_t stream) {
    const float* x    = (const float*)d_in[0];
    const int*   mask = (const int*)d_in[1];
    const float* wq   = (const float*)d_in[2];
    const float* bq   = (const float*)d_in[3];
    const float* wk   = (const float*)d_in[4];
    const float* bk   = (const float*)d_in[5];
    const float* wv   = (const float*)d_in[6];
    const float* bv   = (const float*)d_in[7];
    const float* wo   = (const float*)d_in[8];
    const float* bo   = (const float*)d_in[9];
    const float* w1   = (const float*)d_in[10];
    const float* b1   = (const float*)d_in[11];
    const float* w2   = (const float*)d_in[12];
    const float* b2   = (const float*)d_in[13];
    const float* ln1a = (const float*)d_in[14];
    const float* ln1b = (const float*)d_in[15];
    const float* ln2a = (const float*)d_in[16];
    const float* ln2b = (const float*)d_in[17];

    const size_t MB = 1048576;
    char* ws = (char*)d_ws;
    const bool big = ws_size >= 88 * MB;

    hipFuncSetAttribute(reinterpret_cast<const void*>(gemm256<0>),
                        hipFuncAttributeMaxDynamicSharedMemorySize, 131072);
    hipFuncSetAttribute(reinterpret_cast<const void*>(gemm256<1>),
                        hipFuncAttributeMaxDynamicSharedMemorySize, 131072);

    u16 *xn, *wqkv, *wo_b, *qkvb, *attnb, *w1_b, *w2_b, *hbuf;
    float *bqkv, *x1;
    if (big) {                                   // peak ~80 MB
        xn    = (u16*)(ws + 0 * MB);
        wqkv  = (u16*)(ws + 8 * MB);
        wo_b  = (u16*)(ws + 14 * MB);
        qkvb  = (u16*)(ws + 16 * MB);
        attnb = (u16*)(ws + 40 * MB);
        x1    = (float*)(ws + 48 * MB);
        w1_b  = (u16*)(ws + 64 * MB);
        w2_b  = (u16*)(ws + 72 * MB);
        hbuf  = (u16*)(ws + 16 * MB);            // qkvb+attnb dead by FFN1
        bqkv  = (float*)(ws + 80 * MB);
    } else {                                     // peak 48 MB
        xn    = (u16*)(ws + 0 * MB);
        wqkv  = (u16*)(ws + 8 * MB);
        wo_b  = (u16*)(ws + 14 * MB);
        qkvb  = (u16*)(ws + 16 * MB);
        attnb = (u16*)(ws + 40 * MB);
        x1    = (float*)(ws + 16 * MB);          // qkvb dead after attn
        w1_b  = (u16*)(ws + 32 * MB);            // qkvb tail, dead after attn
        w2_b  = (u16*)(ws + 8 * MB);             // wqkv+wo_b dead after O-proj
        hbuf  = (u16*)(ws + 40 * MB);            // attnb dead after O-proj
        bqkv  = (float*)(ws + 40 * MB);          // dead before attnb written
    }

    pack1_kernel<<<2048, 256, 0, stream>>>(wq, wk, wv, bq, bk, bv, wo, w1, w2,
                                           wqkv, bqkv, wo_b, w1_b, w2_b, big ? 1 : 0);
    ln_kernel<<<4096, 256, 0, stream>>>(x, xn, ln1a, ln1b);
    gemm256<0><<<192, 512, 131072, stream>>>(xn, wqkv, bqkv, qkvb, 1024, 3072, 16);
    attn_kernel<<<1024, 256, 0, stream>>>(qkvb, mask, attnb);
    gemm_bt<2><<<dim3(32, 8), 256, 0, stream>>>(attnb, wo_b, bo, x, x1,
                                                4096, 1024, 1024, 1024);
    ln_kernel<<<4096, 256, 0, stream>>>(x1, xn, ln2a, ln2b);

    if (big) {
        gemm256<1><<<256, 512, 131072, stream>>>(xn, w1_b, b1, hbuf, 1024, 4096, 16);
        gemm_bt<2><<<dim3(32, 8), 256, 0, stream>>>(hbuf, w2_b, b2, x1, (float*)d_out,
                                                    4096, 1024, 4096, 1024);
    } else {
        pack2_kernel<<<1024, 256, 0, stream>>>(w1, w2, w1_b, w2_b);
        const int mrows = 1024;
        for (int cidx = 0; cidx < 4; ++cidx) {
            const size_t ro = (size_t)cidx * mrows;
            gemm_bt<1><<<dim3(mrows / 128, 32), 256, 0, stream>>>(
                xn + ro * 1024, w1_b, b1, nullptr, hbuf, mrows, 4096, 1024, 4096);
            gemm_bt<2><<<dim3(mrows / 128, 8), 256, 0, stream>>>(
                hbuf, w2_b, b2, x1 + ro * 1024, (float*)d_out + ro * 1024,
                mrows, 1024, 4096, 1024);
        }
    }
}

// Round 20
// 282.978 us; speedup vs baseline: 1.0451x; 1.0451x over previous
//
#include <hip/hip_runtime.h>
#include <hip/hip_bf16.h>
#include <stdint.h>

typedef __bf16 bf16x8 __attribute__((ext_vector_type(8)));
typedef __bf16 bf16x4 __attribute__((ext_vector_type(4)));
typedef short  s16x4  __attribute__((ext_vector_type(4)));
typedef float  f32x4  __attribute__((ext_vector_type(4)));
typedef unsigned short u16;

__device__ __forceinline__ u16 f2bf(float f) {
    return __builtin_bit_cast(u16, (__bf16)f);
}

__device__ __forceinline__ f32x4 vexp4(f32x4 a) {
    f32x4 r;
    r[0] = __expf(a[0]); r[1] = __expf(a[1]);
    r[2] = __expf(a[2]); r[3] = __expf(a[3]);
    return r;
}

// 16x16x16 bf16 MFMA (A/B = 4 bf16 = 2 VGPRs each)
__device__ __forceinline__ f32x4 mfma16(bf16x4 a, bf16x4 b, f32x4 c) {
#if __has_builtin(__builtin_amdgcn_mfma_f32_16x16x16bf16_1k)
    return __builtin_amdgcn_mfma_f32_16x16x16bf16_1k(
        __builtin_bit_cast(s16x4, a), __builtin_bit_cast(s16x4, b), c, 0, 0, 0);
#else
    f32x4 d;
    asm volatile("v_mfma_f32_16x16x16_bf16 %0, %1, %2, %3"
                 : "=v"(d) : "v"(a), "v"(b), "v"(c));
    return d;
#endif
}

// async global->LDS, 16B/lane; lds dst is wave-uniform base (+lane*16 implicit)
__device__ __forceinline__ void stage16(const void* g, void* lds_wave_base) {
#if __has_builtin(__builtin_amdgcn_global_load_lds)
    __builtin_amdgcn_global_load_lds(
        (const __attribute__((address_space(1))) void*)g,
        (__attribute__((address_space(3))) void*)lds_wave_base, 16, 0, 0);
#else
    int lane = threadIdx.x & 63;
    *(uint4*)((char*)lds_wave_base + lane * 16) = *(const uint4*)g;
#endif
}

// LDS row swizzle (128B rows): XOR bits 4-6 of the in-row byte offset
__device__ __forceinline__ int swz(int r) {
    return (((r) & 7) ^ (((r) >> 3) & 7)) << 4;
}
// 4-bit swizzle for 256B rows (Vsm): slot = (r&15)^(r>>4), 16 slots
__device__ __forceinline__ int vswz(int r) {
    return (((r) & 15) ^ ((r) >> 4)) << 4;
}

// ---------------------------------------------------------------------------
// pack1: qkv weights (wq scaled 0.125) + wo -> bf16; FFN weights too when
// do_ffn (big path; removes the separate pack2 launch).
// ---------------------------------------------------------------------------
__global__ void pack1_kernel(const float* __restrict__ wq, const float* __restrict__ wk,
                             const float* __restrict__ wv, const float* __restrict__ bq,
                             const float* __restrict__ bk, const float* __restrict__ bv,
                             const float* __restrict__ wo, const float* __restrict__ w1,
                             const float* __restrict__ w2,
                             u16* __restrict__ wqkv, float* __restrict__ bqkv,
                             u16* __restrict__ wo_b, u16* __restrict__ w1_b,
                             u16* __restrict__ w2_b, int do_ffn) {
    const float QS = 0.125f;
    size_t i0 = (size_t)blockIdx.x * 256 + threadIdx.x;
    size_t stride = (size_t)gridDim.x * 256;
    const size_t DD = 1024u * 1024u;
    for (size_t i = i0; i < 3 * DD; i += stride) {
        float v;
        if (i < DD)          v = wq[i] * QS;
        else if (i < 2 * DD) v = wk[i - DD];
        else                 v = wv[i - 2 * DD];
        wqkv[i] = f2bf(v);
    }
    for (size_t i = i0; i < DD; i += stride) wo_b[i] = f2bf(wo[i]);
    if (do_ffn) {
        for (size_t i = i0; i < 4 * DD; i += stride) w1_b[i] = f2bf(w1[i]);
        for (size_t i = i0; i < 4 * DD; i += stride) w2_b[i] = f2bf(w2[i]);
    }
    for (size_t i = i0; i < 3072; i += stride)
        bqkv[i] = (i < 1024) ? bq[i] * QS : ((i < 2048) ? bk[i - 1024] : bv[i - 2048]);
}

// pack2: FFN weights -> bf16 (small path only: runs after O-proj, region reuse)
__global__ void pack2_kernel(const float* __restrict__ w1, const float* __restrict__ w2,
                             u16* __restrict__ w1_b, u16* __restrict__ w2_b) {
    size_t i0 = (size_t)blockIdx.x * 256 + threadIdx.x;
    size_t stride = (size_t)gridDim.x * 256;
    const size_t DD = 1024u * 1024u;
    for (size_t i = i0; i < 4 * DD; i += stride) w1_b[i] = f2bf(w1[i]);
    for (size_t i = i0; i < 4 * DD; i += stride) w2_b[i] = f2bf(w2[i]);
}

// ---------------------------------------------------------------------------
// LayerNorm: per-row (1024), scalar alpha/bias, ddof=1, eps added to std
// ---------------------------------------------------------------------------
__global__ __launch_bounds__(256)
void ln_kernel(const float* __restrict__ x, u16* __restrict__ out,
               const float* __restrict__ alpha, const float* __restrict__ beta) {
    const int row = blockIdx.x;
    const int t = threadIdx.x, lane = t & 63, w = t >> 6;
    float4 v = ((const float4*)(x + (size_t)row * 1024))[t];
    float s  = v.x + v.y + v.z + v.w;
    float ss = v.x * v.x + v.y * v.y + v.z * v.z + v.w * v.w;
#pragma unroll
    for (int d = 1; d < 64; d <<= 1) { s += __shfl_xor(s, d); ss += __shfl_xor(ss, d); }
    __shared__ float red[8];
    if (lane == 0) { red[w] = s; red[4 + w] = ss; }
    __syncthreads();
    s  = red[0] + red[1] + red[2] + red[3];
    ss = red[4] + red[5] + red[6] + red[7];
    const float mu  = s * (1.f / 1024.f);
    const float var = fmaxf((ss - 1024.f * mu * mu) * (1.f / 1023.f), 0.f);
    const float inv = alpha[0] / (sqrtf(var) + 1e-6f);
    const float bb  = beta[0];
    ushort4 o;
    o.x = f2bf((v.x - mu) * inv + bb);
    o.y = f2bf((v.y - mu) * inv + bb);
    o.z = f2bf((v.z - mu) * inv + bb);
    o.w = f2bf((v.w - mu) * inv + bb);
    ((ushort4*)(out + (size_t)row * 1024))[t] = o;
}

// ---------------------------------------------------------------------------
// GEMM 128x128 2-phase, 4 waves (proven): C = A * B^T + bias. BK=32.
// EPI: 0 = bf16 out; 1 = bf16 relu; 2 = f32 out + resid
// ---------------------------------------------------------------------------
template <int EPI>
__global__ __launch_bounds__(256)
void gemm_bt(const u16* __restrict__ A, const u16* __restrict__ B,
             const float* __restrict__ bias, const float* __restrict__ resid,
             void* __restrict__ Cout, int M, int N, int K, int ldc) {
    __shared__ __align__(16) char As[16384];   // 2 x 8192
    __shared__ __align__(16) char Bs[16384];
    const int t = threadIdx.x;
    const int lane = t & 63, wave = t >> 6;
    const int g = lane >> 4, c = lane & 15;
    const int wm = wave >> 1, wn = wave & 1;
    const int bm = blockIdx.x, bn = blockIdx.y;

    const f32x4 z4 = {0.f, 0.f, 0.f, 0.f};
    f32x4 acc[4][4];
#pragma unroll
    for (int m = 0; m < 4; ++m)
#pragma unroll
        for (int n = 0; n < 4; ++n) acc[m][n] = z4;

    const int srow = t >> 2;
    const int ak = (((t & 3) ^ ((t >> 2) & 3)) << 3);
    const u16* ga = A + (size_t)(bm * 128 + srow) * K + ak;
    const u16* gb = B + (size_t)(bn * 128 + srow) * K + ak;
    const size_t rstep = (size_t)64 * K;

    auto STAGE = [&](int k0, int buf) {
        char* la = As + buf * 8192 + wave * 1024;
        char* lb = Bs + buf * 8192 + wave * 1024;
        stage16(ga + k0,         la);
        stage16(ga + k0 + rstep, la + 4096);
        stage16(gb + k0,         lb);
        stage16(gb + k0 + rstep, lb + 4096);
    };

    STAGE(0, 0);
    asm volatile("s_waitcnt vmcnt(0)" ::: "memory");
    __syncthreads();

    int cur = 0;
    for (int k0 = 0; k0 < K; k0 += 32) {
        if (k0 + 32 < K) STAGE(k0 + 32, cur ^ 1);
        const char* Ac = As + cur * 8192;
        const char* Bc = Bs + cur * 8192;
        bf16x8 a[4], b[4];
#pragma unroll
        for (int m = 0; m < 4; ++m) {
            int r = wm * 64 + m * 16 + c;
            a[m] = *(const bf16x8*)(Ac + r * 64 + ((g * 16) ^ ((c & 3) << 4)));
        }
#pragma unroll
        for (int n = 0; n < 4; ++n) {
            int r = wn * 64 + n * 16 + c;
            b[n] = *(const bf16x8*)(Bc + r * 64 + ((g * 16) ^ ((c & 3) << 4)));
        }
        __builtin_amdgcn_s_setprio(1);
#pragma unroll
        for (int m = 0; m < 4; ++m)
#pragma unroll
            for (int n = 0; n < 4; ++n)
                acc[m][n] = __builtin_amdgcn_mfma_f32_16x16x32_bf16(a[m], b[n], acc[m][n], 0, 0, 0);
        __builtin_amdgcn_s_setprio(0);
        asm volatile("s_waitcnt vmcnt(0)" ::: "memory");
        __syncthreads();
        cur ^= 1;
    }

    const int row0 = bm * 128 + wm * 64;
    const int col0 = bn * 128 + wn * 64;
#pragma unroll
    for (int m = 0; m < 4; ++m) {
#pragma unroll
        for (int n = 0; n < 4; ++n) {
            const int cc = col0 + n * 16 + c;
            const float bv = bias[cc];
#pragma unroll
            for (int j = 0; j < 4; ++j) {
                const int rr = row0 + m * 16 + g * 4 + j;
                float v = acc[m][n][j] + bv;
                if (EPI == 1) v = v > 0.f ? v : 0.f;
                if (EPI == 2) {
                    ((float*)Cout)[(size_t)rr * ldc + cc] = resid[(size_t)rr * ldc + cc] + v;
                } else {
                    ((u16*)Cout)[(size_t)rr * ldc + cc] = f2bf(v);
                }
            }
        }
    }
}

// ---------------------------------------------------------------------------
// GEMM 256x256 8-wave 4-phase: C = A*B^T + bias, BK=64. 512 thr (2M x 4N).
// LDS 128KB dynamic. Raw s_barrier per phase; vmcnt(0)+barrier per K-tile.
// EPI: 0 = bf16 out; 1 = bf16 relu.  Grid: 1-D gm*gn, XCD-swizzled (nb%8==0).
// ---------------------------------------------------------------------------
template <int EPI>
__global__ __launch_bounds__(512)
void gemm256(const u16* __restrict__ A, const u16* __restrict__ B,
             const float* __restrict__ bias, u16* __restrict__ Cout,
             int K, int ldc, int gm) {
    extern __shared__ __align__(16) char lds[];
    char* As0 = lds;              // 2 x 32768
    char* Bs0 = lds + 65536;      // 2 x 32768
    const int t = threadIdx.x, lane = t & 63, wave = t >> 6;
    const int g = lane >> 4, c = lane & 15;
    const int wm = wave >> 2, wn = wave & 3;
    const int f = blockIdx.x, nb = gridDim.x;
    const int sw = (f & 7) * (nb >> 3) + (f >> 3);
    const int bm = sw % gm, bn = sw / gm;

    const f32x4 z4 = {0.f, 0.f, 0.f, 0.f};
    f32x4 acc[8][4];
#pragma unroll
    for (int mi = 0; mi < 8; ++mi)
#pragma unroll
        for (int ni = 0; ni < 4; ++ni) acc[mi][ni] = z4;

    auto STAGE = [&](const u16* G, int base_row, int k0, char* dst, int half) {
#pragma unroll
        for (int l = 0; l < 2; ++l) {
            int idx = half * 1024 + l * 512 + t;
            int row = idx >> 3, p = idx & 7;
            stage16(G + (size_t)(base_row + row) * K + k0 + ((p ^ (row & 7)) << 3),
                    dst + (half * 1024 + l * 512 + wave * 64) * 16);
        }
    };
    auto ldA = [&](int buf, int mi, int ks) -> bf16x8 {
        int r = wm * 128 + mi * 16 + c;
        return *(const bf16x8*)(As0 + buf * 32768 + r * 128 + ((((ks << 2) + g) ^ (r & 7)) << 4));
    };
    auto ldB = [&](int buf, int ni, int ks) -> bf16x8 {
        int r = wn * 64 + ni * 16 + c;
        return *(const bf16x8*)(Bs0 + buf * 32768 + r * 128 + ((((ks << 2) + g) ^ (r & 7)) << 4));
    };

    const int NT = K >> 6;
    STAGE(A, bm * 256, 0, As0, 0); STAGE(A, bm * 256, 0, As0, 1);
    STAGE(B, bn * 256, 0, Bs0, 0); STAGE(B, bn * 256, 0, Bs0, 1);
    asm volatile("s_waitcnt vmcnt(0)" ::: "memory");
    __builtin_amdgcn_s_barrier();

    int cur = 0;
    for (int kt = 0; kt < NT; ++kt) {
        const int k0n = (kt + 1) << 6;
        const bool more = kt + 1 < NT;
        bf16x8 bfr[4][2];
#pragma unroll
        for (int ni = 0; ni < 4; ++ni) {
            bfr[ni][0] = ldB(cur, ni, 0);
            bfr[ni][1] = ldB(cur, ni, 1);
        }
#pragma unroll
        for (int ph = 0; ph < 4; ++ph) {
            bf16x8 a0k0 = ldA(cur, 2 * ph, 0),     a0k1 = ldA(cur, 2 * ph, 1);
            bf16x8 a1k0 = ldA(cur, 2 * ph + 1, 0), a1k1 = ldA(cur, 2 * ph + 1, 1);
            if (more && ph == 0) {
                STAGE(A, bm * 256, k0n, As0 + (cur ^ 1) * 32768, 0);
                STAGE(A, bm * 256, k0n, As0 + (cur ^ 1) * 32768, 1);
            }
            if (more && ph == 1) {
                STAGE(B, bn * 256, k0n, Bs0 + (cur ^ 1) * 32768, 0);
                STAGE(B, bn * 256, k0n, Bs0 + (cur ^ 1) * 32768, 1);
            }
            __builtin_amdgcn_s_barrier();
            __builtin_amdgcn_s_setprio(1);
#pragma unroll
            for (int ni = 0; ni < 4; ++ni) {
                acc[2 * ph][ni]     = __builtin_amdgcn_mfma_f32_16x16x32_bf16(a0k0, bfr[ni][0], acc[2 * ph][ni], 0, 0, 0);
                acc[2 * ph][ni]     = __builtin_amdgcn_mfma_f32_16x16x32_bf16(a0k1, bfr[ni][1], acc[2 * ph][ni], 0, 0, 0);
                acc[2 * ph + 1][ni] = __builtin_amdgcn_mfma_f32_16x16x32_bf16(a1k0, bfr[ni][0], acc[2 * ph + 1][ni], 0, 0, 0);
                acc[2 * ph + 1][ni] = __builtin_amdgcn_mfma_f32_16x16x32_bf16(a1k1, bfr[ni][1], acc[2 * ph + 1][ni], 0, 0, 0);
            }
            __builtin_amdgcn_s_setprio(0);
            __builtin_amdgcn_s_barrier();
        }
        asm volatile("s_waitcnt vmcnt(0)" ::: "memory");
        __builtin_amdgcn_s_barrier();
        cur ^= 1;
    }

    const int row0 = bm * 256 + wm * 128;
    const int col0 = bn * 256 + wn * 64;
#pragma unroll
    for (int mi = 0; mi < 8; ++mi) {
#pragma unroll
        for (int ni = 0; ni < 4; ++ni) {
            const int cc = col0 + ni * 16 + c;
            const float bv = bias[cc];
#pragma unroll
            for (int j = 0; j < 4; ++j) {
                const int rr = row0 + mi * 16 + g * 4 + j;
                float v = acc[mi][ni][j] + bv;
                if (EPI == 1) v = v > 0.f ? v : 0.f;
                Cout[(size_t)rr * ldc + cc] = f2bf(v);
            }
        }
    }
}

// ---------------------------------------------------------------------------
// Flash attention (best: R16/R18): QBLK=64 (4 waves x 16 q), KVBLK=128,
// grid 1024, XCD-swz. LDS 48KB: K dbuf (2x16KB), V single (16KB, vswz).
// FIXED-MAX softmax (m==0); l per-lane partial, reduced once in epilogue.
// qkv: [4096,3072] bf16 (q|k|v), q pre-scaled by 0.125. out: [4096,1024] bf16
// ---------------------------------------------------------------------------
__global__ __launch_bounds__(256)
void attn_kernel(const u16* __restrict__ qkv, const int* __restrict__ mask,
                 u16* __restrict__ attn_out) {
    __shared__ __align__(16) char Ksm[32768];   // 2 x [128 k][64 d], src-preswizzled
    __shared__ __align__(16) char Vsm[16384];   // [64 d][128 k] transposed, vswz
    const int t = threadIdx.x, lane = t & 63, w = t >> 6;
    const int g = lane >> 4, c = lane & 15;
    const int flat = blockIdx.x;
    const int xcd = flat & 7, u = flat >> 3;
    const int qt = u & 31;
    const int p = xcd * 4 + (u >> 5);
    const int h = p & 15, b = p >> 4;
    const int S = 2048, LD = 3072;
    const int NT = S / 128;

    bf16x8 qf[2];
#pragma unroll
    for (int half = 0; half < 2; ++half)
        qf[half] = *(const bf16x8*)&qkv[(size_t)(b * S + qt * 64 + w * 16 + c) * LD
                                        + h * 64 + half * 32 + g * 8];

    const f32x4 z4 = {0.f, 0.f, 0.f, 0.f};
    f32x4 accO[4];
#pragma unroll
    for (int dt = 0; dt < 4; ++dt) accO[dt] = z4;
    f32x4 lrun4 = z4;                       // per-lane partial sum of P

    unsigned vr[2][8];
    const int vd0 = (t & 31) * 2;
    const int vkg[2] = {t >> 5, 8 + (t >> 5)};

    auto STAGEK = [&](int kt, char* Kd) {
#pragma unroll
        for (int it = 0; it < 4; ++it) {
            int idx = it * 256 + t;
            int k = idx >> 3, pp = idx & 7;
            int ps = pp ^ ((k & 7) ^ ((k >> 3) & 7));
            stage16(&qkv[(size_t)(b * S + kt * 128 + k) * LD + 1024 + h * 64 + ps * 8],
                    Kd + (it * 256 + w * 64) * 16);
        }
    };
    auto VLOAD = [&](int kt) {
#pragma unroll
        for (int it = 0; it < 2; ++it) {
            const u16* src = &qkv[(size_t)(b * S + kt * 128 + vkg[it] * 8) * LD + 2048 + h * 64 + vd0];
#pragma unroll
            for (int i = 0; i < 8; ++i)
                vr[it][i] = *(const unsigned*)(src + (size_t)i * LD);
        }
    };
    auto VWRITE = [&]() {
#pragma unroll
        for (int it = 0; it < 2; ++it) {
            int d0 = vd0, kg = vkg[it];
            uint4 lo, hi;
            lo.x = (vr[it][0] & 0xffffu) | (vr[it][1] << 16);
            lo.y = (vr[it][2] & 0xffffu) | (vr[it][3] << 16);
            lo.z = (vr[it][4] & 0xffffu) | (vr[it][5] << 16);
            lo.w = (vr[it][6] & 0xffffu) | (vr[it][7] << 16);
            hi.x = (vr[it][0] >> 16) | (vr[it][1] & 0xffff0000u);
            hi.y = (vr[it][2] >> 16) | (vr[it][3] & 0xffff0000u);
            hi.z = (vr[it][4] >> 16) | (vr[it][5] & 0xffff0000u);
            hi.w = (vr[it][6] >> 16) | (vr[it][7] & 0xffff0000u);
            *(uint4*)(Vsm + d0 * 256 + ((kg * 16) ^ vswz(d0)))           = lo;
            *(uint4*)(Vsm + (d0 + 1) * 256 + ((kg * 16) ^ vswz(d0 + 1))) = hi;
        }
    };

    STAGEK(0, Ksm);
    VLOAD(0);
    asm volatile("s_waitcnt vmcnt(0)" ::: "memory");
    VWRITE();
    __syncthreads();

    int cur = 0;
    for (int kt = 0; kt < NT; ++kt) {
        char* Kc = Ksm + cur * 16384;
        if (kt + 1 < NT) {
            STAGEK(kt + 1, Ksm + (cur ^ 1) * 16384);
            VLOAD(kt + 1);
        }

        f32x4 s[8];
        __builtin_amdgcn_s_setprio(1);
#pragma unroll
        for (int n = 0; n < 8; ++n) {
            int kr = n * 16 + c;
            bf16x8 k0 = *(const bf16x8*)(Kc + kr * 128 + ((g * 16) ^ swz(kr)));
            bf16x8 k1 = *(const bf16x8*)(Kc + kr * 128 + ((64 + g * 16) ^ swz(kr)));
            s[n] = __builtin_amdgcn_mfma_f32_16x16x32_bf16(k0, qf[0], z4, 0, 0, 0);
            s[n] = __builtin_amdgcn_mfma_f32_16x16x32_bf16(k1, qf[1], s[n], 0, 0, 0);
        }
        __builtin_amdgcn_s_setprio(0);
#pragma unroll
        for (int n = 0; n < 8; ++n) {
            int4 mv = *(const int4*)&mask[b * S + kt * 128 + n * 16 + g * 4];
            if (mv.x == 0) s[n][0] = -1e9f;
            if (mv.y == 0) s[n][1] = -1e9f;
            if (mv.z == 0) s[n][2] = -1e9f;
            if (mv.w == 0) s[n][3] = -1e9f;
        }
        // fixed-max softmax: P = exp(s); accumulate per-lane partial l
#pragma unroll
        for (int n = 0; n < 8; ++n) { s[n] = vexp4(s[n]); lrun4 += s[n]; }
        __builtin_amdgcn_s_setprio(1);
#pragma unroll
        for (int n = 0; n < 8; ++n) {
            bf16x4 p0;
#pragma unroll
            for (int j = 0; j < 4; ++j) p0[j] = (__bf16)s[n][j];
#pragma unroll
            for (int dt = 0; dt < 4; ++dt) {
                int d = dt * 16 + c;
                bf16x4 vf = *(const bf16x4*)(Vsm + d * 256 + ((n * 32 + g * 8) ^ vswz(d)));
                accO[dt] = mfma16(vf, p0, accO[dt]);
            }
        }
        __builtin_amdgcn_s_setprio(0);

        __syncthreads();
        asm volatile("s_waitcnt vmcnt(0)" ::: "memory");
        if (kt + 1 < NT) VWRITE();
        __syncthreads();
        cur ^= 1;
    }

    // epilogue: reduce l across the 4 covering lanes (once), normalize, store
    char* Osm = Ksm;
    {
        float l = lrun4[0] + lrun4[1] + lrun4[2] + lrun4[3];
        l += __shfl_xor(l, 16);
        l += __shfl_xor(l, 32);
        float inv = 1.f / l;
        int ql = w * 16 + c;
#pragma unroll
        for (int dt = 0; dt < 4; ++dt)
#pragma unroll
            for (int j = 0; j < 4; ++j) {
                int d = dt * 16 + g * 4 + j;
                *(u16*)(Osm + ql * 128 + ((d * 2) ^ swz(ql))) = f2bf(accO[dt][j] * inv);
            }
    }
    __syncthreads();
#pragma unroll
    for (int it = 0; it < 2; ++it) {
        int idx = it * 256 + t;
        int q = idx >> 3, pp = idx & 7;
        uint4 val = *(const uint4*)(Osm + q * 128 + ((pp * 16) ^ swz(q)));
        *(uint4*)&attn_out[(size_t)(b * S + qt * 64 + q) * 1024 + h * 64 + pp * 8] = val;
    }
}

// ---------------------------------------------------------------------------
extern "C" void kernel_launch(void* const* d_in, const int* in_sizes, int n_in,
                              void* d_out, int out_size, void* d_ws, size_t ws_size,
                              hipStream_t stream) {
    const float* x    = (const float*)d_in[0];
    const int*   mask = (const int*)d_in[1];
    const float* wq   = (const float*)d_in[2];
    const float* bq   = (const float*)d_in[3];
    const float* wk   = (const float*)d_in[4];
    const float* bk   = (const float*)d_in[5];
    const float* wv   = (const float*)d_in[6];
    const float* bv   = (const float*)d_in[7];
    const float* wo   = (const float*)d_in[8];
    const float* bo   = (const float*)d_in[9];
    const float* w1   = (const float*)d_in[10];
    const float* b1   = (const float*)d_in[11];
    const float* w2   = (const float*)d_in[12];
    const float* b2   = (const float*)d_in[13];
    const float* ln1a = (const float*)d_in[14];
    const float* ln1b = (const float*)d_in[15];
    const float* ln2a = (const float*)d_in[16];
    const float* ln2b = (const float*)d_in[17];

    const size_t MB = 1048576;
    char* ws = (char*)d_ws;
    const bool big = ws_size >= 88 * MB;

    hipFuncSetAttribute(reinterpret_cast<const void*>(gemm256<0>),
                        hipFuncAttributeMaxDynamicSharedMemorySize, 131072);
    hipFuncSetAttribute(reinterpret_cast<const void*>(gemm256<1>),
                        hipFuncAttributeMaxDynamicSharedMemorySize, 131072);

    u16 *xn, *wqkv, *wo_b, *qkvb, *attnb, *w1_b, *w2_b, *hbuf;
    float *bqkv, *x1;
    if (big) {                                   // peak ~80 MB
        xn    = (u16*)(ws + 0 * MB);
        wqkv  = (u16*)(ws + 8 * MB);
        wo_b  = (u16*)(ws + 14 * MB);
        qkvb  = (u16*)(ws + 16 * MB);
        attnb = (u16*)(ws + 40 * MB);
        x1    = (float*)(ws + 48 * MB);
        w1_b  = (u16*)(ws + 64 * MB);
        w2_b  = (u16*)(ws + 72 * MB);
        hbuf  = (u16*)(ws + 16 * MB);            // qkvb+attnb dead by FFN1
        bqkv  = (float*)(ws + 80 * MB);
    } else {                                     // peak 48 MB
        xn    = (u16*)(ws + 0 * MB);
        wqkv  = (u16*)(ws + 8 * MB);
        wo_b  = (u16*)(ws + 14 * MB);
        qkvb  = (u16*)(ws + 16 * MB);
        attnb = (u16*)(ws + 40 * MB);
        x1    = (float*)(ws + 16 * MB);          // qkvb dead after attn
        w1_b  = (u16*)(ws + 32 * MB);            // qkvb tail, dead after attn
        w2_b  = (u16*)(ws + 8 * MB);             // wqkv+wo_b dead after O-proj
        hbuf  = (u16*)(ws + 40 * MB);            // attnb dead after O-proj
        bqkv  = (float*)(ws + 40 * MB);          // dead before attnb written
    }

    pack1_kernel<<<2048, 256, 0, stream>>>(wq, wk, wv, bq, bk, bv, wo, w1, w2,
                                           wqkv, bqkv, wo_b, w1_b, w2_b, big ? 1 : 0);
    ln_kernel<<<4096, 256, 0, stream>>>(x, xn, ln1a, ln1b);
    gemm256<0><<<192, 512, 131072, stream>>>(xn, wqkv, bqkv, qkvb, 1024, 3072, 16);
    attn_kernel<<<1024, 256, 0, stream>>>(qkvb, mask, attnb);
    gemm_bt<2><<<dim3(32, 8), 256, 0, stream>>>(attnb, wo_b, bo, x, x1,
                                                4096, 1024, 1024, 1024);
    ln_kernel<<<4096, 256, 0, stream>>>(x1, xn, ln2a, ln2b);

    if (big) {
        gemm256<1><<<256, 512, 131072, stream>>>(xn, w1_b, b1, hbuf, 1024, 4096, 16);
        gemm_bt<2><<<dim3(32, 8), 256, 0, stream>>>(hbuf, w2_b, b2, x1, (float*)d_out,
                                                    4096, 1024, 4096, 1024);
    } else {
        pack2_kernel<<<1024, 256, 0, stream>>>(w1, w2, w1_b, w2_b);
        const int mrows = 1024;
        for (int cidx = 0; cidx < 4; ++cidx) {
            const size_t ro = (size_t)cidx * mrows;
            gemm_bt<1><<<dim3(mrows / 128, 32), 256, 0, stream>>>(
                xn + ro * 1024, w1_b, b1, nullptr, hbuf, mrows, 4096, 1024, 4096);
            gemm_bt<2><<<dim3(mrows / 128, 8), 256, 0, stream>>>(
                hbuf, w2_b, b2, x1 + ro * 1024, (float*)d_out + ro * 1024,
                mrows, 1024, 4096, 1024);
        }
    }
}